// Round 11
// baseline (568.263 us; speedup 1.0000x reference)
//
#include <hip/hip_runtime.h>
#include <hip/hip_bf16.h>

typedef __hip_bfloat16 bf16;
typedef __attribute__((ext_vector_type(8))) short bf8v;   // 8 bf16 (4 VGPRs)
typedef __attribute__((ext_vector_type(4))) short s4v;
typedef __attribute__((ext_vector_type(4))) float f4v;

#define DEV __device__ __forceinline__

DEV float b2f(bf16 v){ return __bfloat162float(v); }
DEV bf16 f2b(float v){ return __float2bfloat16(v); }
DEV short f2bs(float v){ bf16 t = __float2bfloat16(v); return *reinterpret_cast<short*>(&t); }
DEV float s2f(short s){ return __uint_as_float(((unsigned int)(unsigned short)s) << 16); }
DEV float rcpf_(float x){ return __builtin_amdgcn_rcpf(x); }
DEV float sigf(float x){ return rcpf_(1.0f + __expf(-x)); }
DEV float tanhfast(float x){
  x = fminf(fmaxf(x, -15.0f), 15.0f);
  float e = __expf(-2.0f*x);
  return (1.0f - e)*rcpf_(1.0f + e);
}

DEV f4v mfma16(bf8v a, bf8v b, f4v c){
  return __builtin_amdgcn_mfma_f32_16x16x32_bf16(a, b, c, 0, 0, 0);
}

// ---------------------------------------------------------------------------
// K0a: dtype detector (fp32 vs bf16 inputs). flag[0]=1 -> bf16, 0 -> fp32.
// ---------------------------------------------------------------------------
__global__ void k_detect(const unsigned int* __restrict__ xw, int* __restrict__ flag){
  __shared__ int found;
  if (threadIdx.x == 0) found = 0;
  __syncthreads();
  int local = 0;
  for (int i = threadIdx.x; i < 4096; i += 256){
    unsigned int u = xw[i];
    unsigned int e = (u >> 7) & 0xFF;
    if (e >= 0x90) local = 1;
  }
  if (local) atomicOr(&found, 1);
  __syncthreads();
  if (threadIdx.x == 0) flag[0] = found ? 0 : 1;
}

// ---------------------------------------------------------------------------
// K0b: canonicalize all float inputs into a bf16 region in ws.
// ---------------------------------------------------------------------------
struct CArgs {
  const void* src[44];
  int n[44];
  int off[44];
};

__global__ void k_canon(CArgs a, const int* __restrict__ flag, bf16* __restrict__ dst){
  int id = blockIdx.y;
  int n = a.n[id];
  const void* s = a.src[id];
  bf16* d = dst + a.off[id];
  int stride = gridDim.x * blockDim.x;
  int i0 = blockIdx.x * blockDim.x + threadIdx.x;
  if (flag[0]){
    const bf16* sb = (const bf16*)s;
    for (int i = i0; i < n; i += stride) d[i] = sb[i];
  } else {
    const float* sf = (const float*)s;
    for (int i = i0; i < n; i += stride) d[i] = f2b(sf[i]);
  }
}

// ---------------------------------------------------------------------------
// K0c: prep padded operands: Wp->Wpp (128x32), A_norm->Anp (112x128),
// zero ht_pad (16x112x128) and hb2_pad (16x112x128).
// ---------------------------------------------------------------------------
__global__ void k_prep(const bf16* __restrict__ Wp, const bf16* __restrict__ An,
                       bf16* __restrict__ Wpp, bf16* __restrict__ Anp,
                       bf16* __restrict__ htp, bf16* __restrict__ hb2p){
  int stride = gridDim.x * blockDim.x;
  bf16 zero = f2b(0.0f);
  for (int i = blockIdx.x*blockDim.x + threadIdx.x; i < 477184; i += stride){
    if (i < 4096){
      int row = i >> 5, col = i & 31;
      Wpp[i] = (col < 26) ? Wp[row*26 + col] : zero;
    } else if (i < 18432){
      int j = i - 4096;
      int row = j >> 7, col = j & 127;
      Anp[j] = (row < 100 && col < 100) ? An[row*100 + col] : zero;
    } else if (i < 247808){
      htp[i - 18432] = zero;
    } else {
      hb2p[i - 247808] = zero;
    }
  }
}

// ---------------------------------------------------------------------------
// K_FAT: fused input-proj + LN + attention + out-proj + residual + LN.
// grid = 1600 (one block per bn), block = 256 (wave = head). LDS 65024 B.
// Regions: h0s (96x136, persists), vre (x-flat -> per-head V^T -> O tile),
// pre (xt -> per-wave transpose scratch -> per-wave P panels, stride 96).
// Q,K,V panels all live in registers during phase 2.
// ---------------------------------------------------------------------------
__global__ __launch_bounds__(256) void k_fat(const bf16* __restrict__ x,
    const bf16* __restrict__ Wpp, const bf16* __restrict__ bp,
    const bf16* __restrict__ gp, const bf16* __restrict__ bbp,
    const bf16* __restrict__ Wqkv, const bf16* __restrict__ bqkv,
    const bf16* __restrict__ Wo, const bf16* __restrict__ bo,
    const bf16* __restrict__ ga, const bf16* __restrict__ ba_,
    bf16* __restrict__ h1){
  int bn = blockIdx.x, tid = threadIdx.x;
  int w = tid >> 6, lane = tid & 63, l15 = lane & 15, quad = lane >> 4;
  __shared__ __align__(16) short h0s[96*136];   // 26112 B
  __shared__ __align__(16) short vre[13312];    // 26624 B: x-flat | V^T | O tile
  __shared__ __align__(16) short pre[6144];     // 12288 B: xt | scr | P panels

  // P0: stage x flat (96x26 bf16 = 312 uint4) into vre
  {
    const uint4* src = (const uint4*)(x + bn*2496);
    uint4* dst = (uint4*)vre;
    for (int u = tid; u < 312; u += 256) dst[u] = src[u];
  }
  __syncthreads();
  // P1: build xt (96x40, cols 26..39 zero) in pre
  for (int i = tid; i < 3840; i += 256){
    int row = i/40, col = i - row*40;
    pre[i] = (col < 26) ? vre[row*26 + col] : (short)0;
  }
  __syncthreads();
  // P2: inproj + bias + LN + relu -> h0s (wave w: m-tiles w, w+4)
  for (int m = w; m < 6; m += 4){
    bf8v a = *reinterpret_cast<const bf8v*>(pre + (m*16 + l15)*40 + quad*8);
    f4v acc[8];
    for (int n = 0; n < 8; ++n){
      bf8v bb = *reinterpret_cast<const bf8v*>(Wpp + (n*16 + l15)*32 + quad*8);
      f4v z = {0.f,0.f,0.f,0.f};
      acc[n] = mfma16(a, bb, z);
    }
    float sm[4], sq[4];
    #pragma unroll
    for (int r = 0; r < 4; ++r){ sm[r] = 0.f; sq[r] = 0.f; }
    #pragma unroll
    for (int n = 0; n < 8; ++n){
      int col = n*16 + l15;
      float bv = b2f(bp[col]);
      #pragma unroll
      for (int r = 0; r < 4; ++r){
        float v = acc[n][r] + bv;
        acc[n][r] = v;
        sm[r] += v; sq[r] += v*v;
      }
    }
    #pragma unroll
    for (int mask = 1; mask < 16; mask <<= 1)
      #pragma unroll
      for (int r = 0; r < 4; ++r){
        sm[r] += __shfl_xor(sm[r], mask);
        sq[r] += __shfl_xor(sq[r], mask);
      }
    #pragma unroll
    for (int r = 0; r < 4; ++r){
      float mean = sm[r]*(1.0f/128.0f);
      float var = fmaxf(sq[r]*(1.0f/128.0f) - mean*mean, 0.0f);
      float rs = rsqrtf(var + 1e-5f);
      #pragma unroll
      for (int n = 0; n < 8; ++n){
        int col = n*16 + l15;
        float y = fmaxf((acc[n][r] - mean)*rs*b2f(gp[col]) + b2f(bbp[col]), 0.0f);
        h0s[(m*16 + quad*4 + r)*136 + col] = f2bs(y);
      }
    }
  }
  __syncthreads();

  short* sw = pre + w*1536;     // per-wave transpose scratch (16x40)
  short* vp = vre + w*3328;     // per-head V^T (32x104)
  const float scl = 0.17677669529663687f;  // 1/sqrt(32), folded into Q

  bf8v aq[6], bk[6], bv[2][3];
  // Phase 1a: Q panels -> registers
  for (int m = 0; m < 6; ++m){
    bf8v a[4];
    #pragma unroll
    for (int kt = 0; kt < 4; ++kt)
      a[kt] = *reinterpret_cast<const bf8v*>(h0s + (m*16 + l15)*136 + kt*32 + quad*8);
    #pragma unroll
    for (int n0 = 0; n0 < 32; n0 += 16){
      int rq = w*32 + n0 + l15;
      bf8v b[4];
      #pragma unroll
      for (int kt = 0; kt < 4; ++kt)
        b[kt] = *reinterpret_cast<const bf8v*>(Wqkv + rq*128 + kt*32 + quad*8);
      float bias = b2f(bqkv[rq]);
      f4v acc = {0.f,0.f,0.f,0.f};
      #pragma unroll
      for (int kt = 0; kt < 4; ++kt) acc = mfma16(a[kt], b[kt], acc);
      #pragma unroll
      for (int r = 0; r < 4; ++r)
        sw[(quad*4 + r)*40 + n0 + l15] = f2bs((acc[r] + bias)*scl);
    }
    asm volatile("s_waitcnt lgkmcnt(0)" ::: "memory");
    aq[m] = *reinterpret_cast<const bf8v*>(sw + l15*40 + quad*8);
  }
  // Phase 1b: K panels -> registers
  for (int m = 0; m < 6; ++m){
    bf8v a[4];
    #pragma unroll
    for (int kt = 0; kt < 4; ++kt)
      a[kt] = *reinterpret_cast<const bf8v*>(h0s + (m*16 + l15)*136 + kt*32 + quad*8);
    #pragma unroll
    for (int n0 = 0; n0 < 32; n0 += 16){
      int rq = 128 + w*32 + n0 + l15;
      bf8v b[4];
      #pragma unroll
      for (int kt = 0; kt < 4; ++kt)
        b[kt] = *reinterpret_cast<const bf8v*>(Wqkv + rq*128 + kt*32 + quad*8);
      float bias = b2f(bqkv[rq]);
      f4v acc = {0.f,0.f,0.f,0.f};
      #pragma unroll
      for (int kt = 0; kt < 4; ++kt) acc = mfma16(a[kt], b[kt], acc);
      #pragma unroll
      for (int r = 0; r < 4; ++r)
        sw[(quad*4 + r)*40 + n0 + l15] = f2bs(acc[r] + bias);
    }
    asm volatile("s_waitcnt lgkmcnt(0)" ::: "memory");
    bk[m] = *reinterpret_cast<const bf8v*>(sw + l15*40 + quad*8);
  }
  // Phase 1c: V^T -> LDS (dim x seq), then into registers
  for (int m = 0; m < 6; ++m){
    bf8v a[4];
    #pragma unroll
    for (int kt = 0; kt < 4; ++kt)
      a[kt] = *reinterpret_cast<const bf8v*>(h0s + (m*16 + l15)*136 + kt*32 + quad*8);
    #pragma unroll
    for (int n0 = 0; n0 < 32; n0 += 16){
      int rq = 256 + w*32 + n0 + l15;
      bf8v b[4];
      #pragma unroll
      for (int kt = 0; kt < 4; ++kt)
        b[kt] = *reinterpret_cast<const bf8v*>(Wqkv + rq*128 + kt*32 + quad*8);
      float bias = b2f(bqkv[rq]);
      f4v acc = {0.f,0.f,0.f,0.f};
      #pragma unroll
      for (int kt = 0; kt < 4; ++kt) acc = mfma16(a[kt], b[kt], acc);
      s4v vs;
      #pragma unroll
      for (int r = 0; r < 4; ++r) vs[r] = f2bs(acc[r] + bias);
      *reinterpret_cast<s4v*>(vp + (n0 + l15)*104 + m*16 + quad*4) = vs;
    }
  }
  asm volatile("s_waitcnt lgkmcnt(0)" ::: "memory");
  #pragma unroll
  for (int n = 0; n < 2; ++n)
    #pragma unroll
    for (int ksi = 0; ksi < 3; ++ksi)
      bv[n][ksi] = *reinterpret_cast<const bf8v*>(vp + (n*16 + l15)*104 + ksi*32 + quad*8);
  __syncthreads();   // all V consumed into regs -> vre becomes the O tile

  short* pp = pre + w*1536;   // 16 x 96 bf16 P panel per wave

  // Phase 2: per m-tile: S = Q K^T (regs), softmax, P V -> O tile (vre)
  for (int m = 0; m < 6; ++m){
    f4v s[6];
    #pragma unroll
    for (int n = 0; n < 6; ++n){
      f4v z = {0.f,0.f,0.f,0.f};
      s[n] = mfma16(aq[m], bk[n], z);
    }
    float mr[4], sr[4];
    #pragma unroll
    for (int r = 0; r < 4; ++r){
      float m0 = fmaxf(fmaxf(s[0][r], s[1][r]), fmaxf(s[2][r], s[3][r]));
      mr[r] = fmaxf(m0, fmaxf(s[4][r], s[5][r]));
    }
    #pragma unroll
    for (int mask = 1; mask < 16; mask <<= 1)
      #pragma unroll
      for (int r = 0; r < 4; ++r) mr[r] = fmaxf(mr[r], __shfl_xor(mr[r], mask));
    #pragma unroll
    for (int r = 0; r < 4; ++r) sr[r] = 0.0f;
    #pragma unroll
    for (int n = 0; n < 6; ++n)
      #pragma unroll
      for (int r = 0; r < 4; ++r){
        float p = __expf(s[n][r] - mr[r]);
        s[n][r] = p;
        sr[r] += p;
      }
    #pragma unroll
    for (int mask = 1; mask < 16; mask <<= 1)
      #pragma unroll
      for (int r = 0; r < 4; ++r) sr[r] += __shfl_xor(sr[r], mask);
    #pragma unroll
    for (int n = 0; n < 6; ++n)
      #pragma unroll
      for (int r = 0; r < 4; ++r)
        pp[(quad*4 + r)*96 + n*16 + l15] = f2bs(s[n][r]);
    asm volatile("s_waitcnt lgkmcnt(0)" ::: "memory");
    f4v o0 = {0.f,0.f,0.f,0.f}, o1 = {0.f,0.f,0.f,0.f};
    #pragma unroll
    for (int ksi = 0; ksi < 3; ++ksi){
      bf8v ap = *reinterpret_cast<const bf8v*>(pp + l15*96 + ksi*32 + quad*8);
      o0 = mfma16(ap, bv[0][ksi], o0);
      o1 = mfma16(ap, bv[1][ksi], o1);
    }
    #pragma unroll
    for (int r = 0; r < 4; ++r){
      float inv = 1.0f/sr[r];
      int row = m*16 + quad*4 + r;
      vre[row*136 + w*32 + l15]      = f2bs(o0[r]*inv);
      vre[row*136 + w*32 + 16 + l15] = f2bs(o1[r]*inv);
    }
  }
  __syncthreads();   // O tile complete

  // P7: out-proj + residual + LN -> h1 (wave w: m-tiles w, w+4)
  for (int m = w; m < 6; m += 4){
    bf8v a[4];
    #pragma unroll
    for (int kt = 0; kt < 4; ++kt)
      a[kt] = *reinterpret_cast<const bf8v*>(vre + (m*16 + l15)*136 + kt*32 + quad*8);
    f4v acc[8];
    for (int n = 0; n < 8; ++n){
      int G = n*16 + l15;
      f4v z = {0.f,0.f,0.f,0.f};
      #pragma unroll
      for (int kt = 0; kt < 4; ++kt){
        bf8v bb = *reinterpret_cast<const bf8v*>(Wo + G*128 + kt*32 + quad*8);
        z = mfma16(a[kt], bb, z);
      }
      acc[n] = z;
    }
    float sm[4], sq[4];
    #pragma unroll
    for (int r = 0; r < 4; ++r){ sm[r] = 0.f; sq[r] = 0.f; }
    #pragma unroll
    for (int n = 0; n < 8; ++n){
      int col = n*16 + l15;
      float bia = b2f(bo[col]);
      #pragma unroll
      for (int r = 0; r < 4; ++r){
        float v = acc[n][r] + bia + s2f(h0s[(m*16 + quad*4 + r)*136 + col]);
        acc[n][r] = v;
        sm[r] += v; sq[r] += v*v;
      }
    }
    #pragma unroll
    for (int mask = 1; mask < 16; mask <<= 1)
      #pragma unroll
      for (int r = 0; r < 4; ++r){
        sm[r] += __shfl_xor(sm[r], mask);
        sq[r] += __shfl_xor(sq[r], mask);
      }
    #pragma unroll
    for (int r = 0; r < 4; ++r){
      float mean = sm[r]*(1.0f/128.0f);
      float var = fmaxf(sq[r]*(1.0f/128.0f) - mean*mean, 0.0f);
      float rs = rsqrtf(var + 1e-5f);
      #pragma unroll
      for (int n = 0; n < 8; ++n){
        int col = n*16 + l15;
        float y = (acc[n][r] - mean)*rs*b2f(ga[col]) + b2f(ba_[col]);
        h1[(bn*96 + m*16 + quad*4 + r)*128 + col] = f2b(y);
      }
    }
  }
}

// ---------------------------------------------------------------------------
// K5: fused forward LSTM + backward single-step + temporal projection.
// grid = 100 (16 samples/block), block = 512 (8 waves).
// ---------------------------------------------------------------------------
__global__ __launch_bounds__(512,1) void k_lstm(const bf16* __restrict__ Whh,
    const bf16* __restrict__ Wih, const bf16* __restrict__ bih,
    const bf16* __restrict__ bhh, const bf16* __restrict__ h1,
    const bf16* __restrict__ Wihb, const bf16* __restrict__ bihb,
    const bf16* __restrict__ bhhb, const bf16* __restrict__ Wtp,
    const bf16* __restrict__ btp, bf16* __restrict__ ht_pad,
    const int* __restrict__ flag, bf16* __restrict__ outb,
    float* __restrict__ outf){
  int bn0 = blockIdx.x * 16;
  int tid = threadIdx.x;
  int w = tid >> 6, lane = tid & 63;
  int l15 = lane & 15, quad = lane >> 4;
  __shared__ __align__(16) short hbuf[2][16*136];
  __shared__ __align__(16) short xbuf[2][16*136];
  __shared__ __align__(16) short ycat[16*264];

  bf8v whh[4][4], wih[4][4];
  float bias[4];
  #pragma unroll
  for (int role = 0; role < 4; ++role){
    int G = role*128 + w*16 + l15;
    #pragma unroll
    for (int kt = 0; kt < 4; ++kt){
      whh[role][kt] = *reinterpret_cast<const bf8v*>(Whh + G*128 + kt*32 + quad*8);
      wih[role][kt] = *reinterpret_cast<const bf8v*>(Wih + G*128 + kt*32 + quad*8);
    }
    bias[role] = b2f(bih[G]) + b2f(bhh[G]);
  }
  const uint4* h1u4 = (const uint4*)h1;
  int srow = tid >> 4, scol = tid & 15;

  for (int i = tid; i < 16*136; i += 512) hbuf[0][i] = 0;
  if (tid < 256)
    ((uint4*)xbuf[0])[srow*17 + scol] = h1u4[((bn0 + srow)*96 + 0)*16 + scol];
  f4v c0 = {0.f,0.f,0.f,0.f};
  uint4 xpre;
  if (tid < 256) xpre = h1u4[((bn0 + srow)*96 + 1)*16 + scol];
  __syncthreads();

  f4v accx[4];
  {
    bf8v ax[4];
    #pragma unroll
    for (int kt = 0; kt < 4; ++kt)
      ax[kt] = *reinterpret_cast<const bf8v*>(xbuf[0] + l15*136 + kt*32 + quad*8);
    #pragma unroll
    for (int role = 0; role < 4; ++role){
      f4v z = {0.f,0.f,0.f,0.f};
      #pragma unroll
      for (int kt = 0; kt < 4; ++kt) z = mfma16(ax[kt], wih[role][kt], z);
      accx[role] = z;
    }
  }
  if (tid < 256) ((uint4*)xbuf[1])[srow*17 + scol] = xpre;
  if (tid < 256) xpre = h1u4[((bn0 + srow)*96 + 2)*16 + scol];
  __syncthreads();

  for (int t = 0; t < 96; ++t){
    int cur = t & 1, nxt = cur ^ 1;
    bf8v ah[4], axn[4];
    #pragma unroll
    for (int kt = 0; kt < 4; ++kt){
      ah[kt]  = *reinterpret_cast<const bf8v*>(hbuf[cur] + l15*136 + kt*32 + quad*8);
      axn[kt] = *reinterpret_cast<const bf8v*>(xbuf[nxt] + l15*136 + kt*32 + quad*8);
    }
    f4v acc[4];
    #pragma unroll
    for (int role = 0; role < 4; ++role){
      f4v z = accx[role];
      #pragma unroll
      for (int kt = 0; kt < 4; ++kt) z = mfma16(ah[kt], whh[role][kt], z);
      acc[role] = z;
    }
    #pragma unroll
    for (int role = 0; role < 4; ++role){
      f4v z = {0.f,0.f,0.f,0.f};
      #pragma unroll
      for (int kt = 0; kt < 4; ++kt) z = mfma16(axn[kt], wih[role][kt], z);
      accx[role] = z;
    }
    float hreg[4];
    #pragma unroll
    for (int r = 0; r < 4; ++r){
      float i_ = acc[0][r] + bias[0];
      float f_ = acc[1][r] + bias[1];
      float g_ = acc[2][r] + bias[2];
      float o_ = acc[3][r] + bias[3];
      float c  = sigf(f_)*c0[r] + sigf(i_)*tanhfast(g_);
      hreg[r]  = sigf(o_)*tanhfast(c);
      c0[r] = c;
    }
    #pragma unroll
    for (int r = 0; r < 4; ++r)
      hbuf[nxt][(quad*4 + r)*136 + w*16 + l15] = f2bs(hreg[r]);
    if (tid < 256){
      ((uint4*)xbuf[cur])[srow*17 + scol] = xpre;
      int tl = (t + 3 < 96) ? t + 3 : 95;
      xpre = h1u4[((bn0 + srow)*96 + tl)*16 + scol];
    }
    __syncthreads();
  }
  // ---- epilogue: bwd single-step (zero state) + Wtp projection ----
  for (int idx = tid; idx < 2048; idx += 512){
    int r = idx >> 7, d = idx & 127;
    ycat[r*264 + d] = hbuf[0][r*136 + d];
  }
  {
    bf8v ax[4];
    #pragma unroll
    for (int kt = 0; kt < 4; ++kt)
      ax[kt] = *reinterpret_cast<const bf8v*>(xbuf[0] + l15*136 + kt*32 + quad*8);
    int col = w*16 + l15;
    f4v gi = {0.f,0.f,0.f,0.f}, gg = {0.f,0.f,0.f,0.f}, go = {0.f,0.f,0.f,0.f};
    #pragma unroll
    for (int kt = 0; kt < 4; ++kt){
      gi = mfma16(ax[kt], *reinterpret_cast<const bf8v*>(Wihb + col*128 + kt*32 + quad*8), gi);
      gg = mfma16(ax[kt], *reinterpret_cast<const bf8v*>(Wihb + (256 + col)*128 + kt*32 + quad*8), gg);
      go = mfma16(ax[kt], *reinterpret_cast<const bf8v*>(Wihb + (384 + col)*128 + kt*32 + quad*8), go);
    }
    float bi = b2f(bihb[col])       + b2f(bhhb[col]);
    float bg = b2f(bihb[256 + col]) + b2f(bhhb[256 + col]);
    float bo = b2f(bihb[384 + col]) + b2f(bhhb[384 + col]);
    #pragma unroll
    for (int r = 0; r < 4; ++r){
      float c  = sigf(gi[r] + bi) * tanhfast(gg[r] + bg);
      float yb = sigf(go[r] + bo) * tanhfast(c);
      ycat[(quad*4 + r)*264 + 128 + col] = f2bs(yb);
    }
  }
  __syncthreads();
  {
    int col = w*16 + l15;
    f4v z = {0.f,0.f,0.f,0.f};
    #pragma unroll
    for (int kt = 0; kt < 8; ++kt){
      bf8v a = *reinterpret_cast<const bf8v*>(ycat + l15*264 + kt*32 + quad*8);
      bf8v bb = *reinterpret_cast<const bf8v*>(Wtp + col*256 + kt*32 + quad*8);
      z = mfma16(a, bb, z);
    }
    float bt = b2f(btp[col]);
    #pragma unroll
    for (int r = 0; r < 4; ++r){
      int rowg = bn0 + quad*4 + r;
      float v = z[r] + bt;
      int bb_ = rowg/100, nn = rowg - bb_*100;
      ht_pad[(bb_*112 + nn)*128 + col] = f2b(v);
      int oi = 206400 + rowg*128 + col;
      if (flag[0]) outb[oi] = f2b(v); else outf[oi] = v;
    }
  }
}

// ---------------------------------------------------------------------------
// K6: spatial part A (hyperedge attention + node LN). grid = 16, block = 512.
// ---------------------------------------------------------------------------
__global__ __launch_bounds__(512,1) void k_spat1(
    const bf16* __restrict__ ht_pad, const bf16* __restrict__ Hinc,
    const bf16* __restrict__ Wn, const bf16* __restrict__ bn_,
    const bf16* __restrict__ We, const bf16* __restrict__ be,
    const bf16* __restrict__ Wa, const bf16* __restrict__ ba,
    const bf16* __restrict__ gg_, const bf16* __restrict__ bg_,
    bf16* __restrict__ hb2g){
  int b = blockIdx.x, tid = threadIdx.x;
  int w = tid >> 6, lane = tid & 63, l15 = lane & 15, quad = lane >> 4;
  __shared__ __align__(16) short htb[112*136];
  __shared__ __align__(16) short mtile[16*136];
  __shared__ float HincS[1600];
  __shared__ float wts[1600];
  __shared__ float eeS[16*128];
  __shared__ float scE[16], degS[16], part[128];

  {
    const uint4* src = (const uint4*)(ht_pad + b*14336);
    uint4* dst = (uint4*)htb;
    for (int u = tid; u < 1792; u += 512){
      int r = u >> 4, c = u & 15;
      dst[r*17 + c] = src[u];
    }
  }
  for (int i = tid; i < 1600; i += 512) HincS[i] = b2f(Hinc[i]);
  __syncthreads();
  if (tid < 16){
    float s = 0.0f;
    for (int n = 0; n < 100; ++n) s += HincS[n*16 + tid];
    degS[tid] = s;
  }
  __syncthreads();
  for (int it = 0; it < 4; ++it){
    int idx = tid + it*512;
    int e = idx >> 7, d = idx & 127;
    float s = 0.0f;
    for (int n = 0; n < 100; ++n)
      s += HincS[n*16 + e] * s2f(htb[n*136 + d]);
    mtile[e*136 + d] = f2bs(s * rcpf_(degS[e] + 1e-8f));
  }
  __syncthreads();
  {
    bf8v a[4];
    #pragma unroll
    for (int kt = 0; kt < 4; ++kt)
      a[kt] = *reinterpret_cast<const bf8v*>(mtile + l15*136 + kt*32 + quad*8);
    int col = w*16 + l15;
    f4v z = {0.f,0.f,0.f,0.f};
    #pragma unroll
    for (int kt = 0; kt < 4; ++kt)
      z = mfma16(a[kt], *reinterpret_cast<const bf8v*>(Wn + col*128 + kt*32 + quad*8), z);
    float bnv = b2f(bn_[col]);
    __syncthreads();
    #pragma unroll
    for (int r = 0; r < 4; ++r){
      int e = quad*4 + r;
      float ratio = degS[e] * rcpf_(degS[e] + 1e-8f);
      mtile[e*136 + col] = f2bs(z[r] + bnv*ratio);
    }
  }
  __syncthreads();
  {
    bf8v a[4];
    #pragma unroll
    for (int kt = 0; kt < 4; ++kt)
      a[kt] = *reinterpret_cast<const bf8v*>(mtile + l15*136 + kt*32 + quad*8);
    int col = w*16 + l15;
    f4v z = {0.f,0.f,0.f,0.f};
    #pragma unroll
    for (int kt = 0; kt < 4; ++kt)
      z = mfma16(a[kt], *reinterpret_cast<const bf8v*>(We + col*128 + kt*32 + quad*8), z);
    float bev = b2f(be[col]);
    #pragma unroll
    for (int r = 0; r < 4; ++r)
      eeS[(quad*4 + r)*128 + col] = z[r] + bev;
  }
  __syncthreads();
  if (tid < 128){
    int e = tid >> 3, j = tid & 7;
    float s = 0.0f;
    for (int d = j*16; d < j*16 + 16; ++d)
      s += eeS[e*128 + d] * b2f(Wa[d]);
    part[tid] = s;
  }
  __syncthreads();
  if (tid < 16){
    float s = b2f(ba[0]);
    for (int j = 0; j < 8; ++j) s += part[tid*8 + j];
    scE[tid] = s;
  }
  __syncthreads();
  if (tid < 100){
    float sc[16], mx = -1e30f;
    for (int e = 0; e < 16; ++e){
      sc[e] = (HincS[tid*16 + e] > 0.0f) ? scE[e] : -1e30f;
      mx = fmaxf(mx, sc[e]);
    }
    float sum = 0.0f, tmp[16];
    for (int e = 0; e < 16; ++e){
      tmp[e] = (sc[e] > -1e29f) ? __expf(sc[e] - mx) : 0.0f;
      sum += tmp[e];
    }
    float inv = (sum > 0.0f) ? rcpf_(sum) : 0.0f;
    for (int e = 0; e < 16; ++e) wts[tid*16 + e] = tmp[e]*inv;
  }
  __syncthreads();
  for (int it = 0; it < 13; ++it){
    int n = it*8 + w;
    if (n < 100){
      int d0 = lane*2;
      float s0 = s2f(htb[n*136 + d0]);
      float s1 = s2f(htb[n*136 + d0 + 1]);
      for (int e = 0; e < 16; ++e){
        float wv = wts[n*16 + e];
        s0 += wv * eeS[e*128 + d0];
        s1 += wv * eeS[e*128 + d0 + 1];
      }
      float sum = s0 + s1, sq = s0*s0 + s1*s1;
      #pragma unroll
      for (int mask = 1; mask < 64; mask <<= 1){
        sum += __shfl_xor(sum, mask);
        sq  += __shfl_xor(sq, mask);
      }
      float mean = sum*(1.0f/128.0f);
      float var = fmaxf(sq*(1.0f/128.0f) - mean*mean, 0.0f);
      float rs = rsqrtf(var + 1e-5f);
      float y0 = (s0 - mean)*rs*b2f(gg_[d0])     + b2f(bg_[d0]);
      float y1 = (s1 - mean)*rs*b2f(gg_[d0 + 1]) + b2f(bg_[d0 + 1]);
      hb2g[b*14336 + n*128 + d0]     = f2b(y0);
      hb2g[b*14336 + n*128 + d0 + 1] = f2b(y1);
    }
  }
}

// ---------------------------------------------------------------------------
// K7: spatial part B (GCN + fusion + head). grid = 16, block = 512.
// ---------------------------------------------------------------------------
__global__ __launch_bounds__(512,1) void k_spat2(
    const bf16* __restrict__ hb2g, const bf16* __restrict__ Anp,
    const bf16* __restrict__ Wg, const bf16* __restrict__ bgc,
    const bf16* __restrict__ Remb, const int* __restrict__ mem,
    const bf16* __restrict__ ht_pad,
    const bf16* __restrict__ Wf, const bf16* __restrict__ bf_,
    const bf16* __restrict__ gf, const bf16* __restrict__ b_f,
    const bf16* __restrict__ W1, const bf16* __restrict__ b1,
    const bf16* __restrict__ W2, const bf16* __restrict__ b2,
    const int* __restrict__ flag, bf16* __restrict__ outb,
    float* __restrict__ outf){
  int b = blockIdx.x, tid = threadIdx.x;
  int w = tid >> 6, lane = tid & 63, l15 = lane & 15, quad = lane >> 4;
  __shared__ __align__(16) short regA[128*136];
  __shared__ __align__(16) short regB[112*136];

  for (int i = tid; i < 128*136; i += 512) regA[i] = 0;
  __syncthreads();
  {
    int c0 = w*16;
    bf8v bw[4];
    #pragma unroll
    for (int kt = 0; kt < 4; ++kt)
      bw[kt] = *reinterpret_cast<const bf8v*>(Wg + (c0 + l15)*128 + kt*32 + quad*8);
    for (int m = 0; m < 7; ++m){
      f4v z = {0.f,0.f,0.f,0.f};
      #pragma unroll
      for (int kt = 0; kt < 4; ++kt){
        bf8v a = *reinterpret_cast<const bf8v*>(hb2g + b*14336 + (m*16 + l15)*128 + kt*32 + quad*8);
        z = mfma16(a, bw[kt], z);
      }
      s4v vs;
      #pragma unroll
      for (int r = 0; r < 4; ++r) vs[r] = f2bs(z[r]);
      *reinterpret_cast<s4v*>(regA + (c0 + l15)*136 + m*16 + quad*4) = vs;
    }
  }
  __syncthreads();
  {
    int c0 = w*16;
    for (int m = 0; m < 7; ++m){
      f4v z = {0.f,0.f,0.f,0.f};
      #pragma unroll
      for (int kt = 0; kt < 4; ++kt){
        bf8v a  = *reinterpret_cast<const bf8v*>(Anp + (m*16 + l15)*128 + kt*32 + quad*8);
        bf8v bb = *reinterpret_cast<const bf8v*>(regA + (c0 + l15)*136 + kt*32 + quad*8);
        z = mfma16(a, bb, z);
      }
      #pragma unroll
      for (int r = 0; r < 4; ++r){
        int row = m*16 + quad*4 + r, col = c0 + l15;
        if (row < 100){
          float v = fmaxf(z[r] + b2f(bgc[col]), 0.0f);
          float o = b2f(hb2g[b*14336 + row*128 + col]) + v
                  + b2f(Remb[mem[row]*128 + col]);
          int oi = 1600 + (b*100 + row)*128 + col;
          if (flag[0]) outb[oi] = f2b(o); else outf[oi] = o;
          regB[row*136 + col] = f2bs(o);
        } else {
          regB[row*136 + col] = 0;
        }
      }
    }
  }
  __syncthreads();
  if (w < 7){
    int m = w;
    f4v acc[8];
    for (int n = 0; n < 8; ++n){
      f4v z = {0.f,0.f,0.f,0.f};
      #pragma unroll
      for (int kt = 0; kt < 4; ++kt){
        bf8v a  = *reinterpret_cast<const bf8v*>(ht_pad + b*14336 + (m*16 + l15)*128 + kt*32 + quad*8);
        bf8v bb = *reinterpret_cast<const bf8v*>(Wf + (n*16 + l15)*256 + kt*32 + quad*8);
        z = mfma16(a, bb, z);
      }
      #pragma unroll
      for (int kt = 0; kt < 4; ++kt){
        bf8v a  = *reinterpret_cast<const bf8v*>(regB + (m*16 + l15)*136 + kt*32 + quad*8);
        bf8v bb = *reinterpret_cast<const bf8v*>(Wf + (n*16 + l15)*256 + 128 + kt*32 + quad*8);
        z = mfma16(a, bb, z);
      }
      acc[n] = z;
    }
    float sm[4], sq[4];
    #pragma unroll
    for (int r = 0; r < 4; ++r){ sm[r] = 0.f; sq[r] = 0.f; }
    #pragma unroll
    for (int n = 0; n < 8; ++n){
      int col = n*16 + l15;
      float bv = b2f(bf_[col]);
      #pragma unroll
      for (int r = 0; r < 4; ++r){
        float v = acc[n][r] + bv;
        acc[n][r] = v;
        sm[r] += v; sq[r] += v*v;
      }
    }
    #pragma unroll
    for (int mask = 1; mask < 16; mask <<= 1)
      #pragma unroll
      for (int r = 0; r < 4; ++r){
        sm[r] += __shfl_xor(sm[r], mask);
        sq[r] += __shfl_xor(sq[r], mask);
      }
    #pragma unroll
    for (int r = 0; r < 4; ++r){
      float mean = sm[r]*(1.0f/128.0f);
      float var = fmaxf(sq[r]*(1.0f/128.0f) - mean*mean, 0.0f);
      float rs = rsqrtf(var + 1e-5f);
      #pragma unroll
      for (int n = 0; n < 8; ++n){
        int col = n*16 + l15;
        float y = fmaxf((acc[n][r] - mean)*rs*b2f(gf[col]) + b2f(b_f[col]), 0.0f);
        regA[(m*16 + quad*4 + r)*136 + col] = f2bs(y);
      }
    }
  }
  __syncthreads();
  if (w < 7){
    int m = w;
    for (int n = 0; n < 4; ++n){
      f4v z = {0.f,0.f,0.f,0.f};
      #pragma unroll
      for (int kt = 0; kt < 4; ++kt){
        bf8v a  = *reinterpret_cast<const bf8v*>(regA + (m*16 + l15)*136 + kt*32 + quad*8);
        bf8v bb = *reinterpret_cast<const bf8v*>(W1 + (n*16 + l15)*128 + kt*32 + quad*8);
        z = mfma16(a, bb, z);
      }
      #pragma unroll
      for (int r = 0; r < 4; ++r){
        int row = m*16 + quad*4 + r, col = n*16 + l15;
        regB[row*72 + col] = f2bs(fmaxf(z[r] + b2f(b1[col]), 0.0f));
      }
    }
  }
  __syncthreads();
  if (tid < 100){
    float s = b2f(b2[0]);
    for (int d = 0; d < 64; ++d)
      s += s2f(regB[tid*72 + d]) * b2f(W2[d]);
    int oi = b*100 + tid;
    if (flag[0]) outb[oi] = f2b(s); else outf[oi] = s;
  }
}

// ---------------------------------------------------------------------------

extern "C" void kernel_launch(void* const* d_in, const int* in_sizes, int n_in,
                              void* d_out, int out_size, void* d_ws, size_t ws_size,
                              hipStream_t stream){
  (void)n_in; (void)out_size; (void)ws_size;
  const int* mem = (const int*)d_in[3];

  CArgs ca;
  int coff[43];
  int nf = 0;
  long long off = 0;
  for (int i = 0; i < 43; ++i){
    if (i == 3){ coff[i] = -1; continue; }
    coff[i] = (int)off;
    ca.src[nf] = d_in[i];
    ca.n[nf]   = in_sizes[i];
    ca.off[nf] = (int)off;
    ++nf;
    off += (long long)((in_sizes[i] + 7) & ~7);
  }
  char* ws = (char*)d_ws;
  bf16* canon = (bf16*)ws;
  long long canonBytes = ((off*2 + 255)/256)*256;
  int* flag = (int*)(ws + canonBytes);
  long long base = canonBytes + 256;

  #define C(i) (canon + coff[i])
  const bf16* A_norm = C(1);
  const bf16* Hinc   = C(2);
  const bf16* Wp  = C(4);  const bf16* bp  = C(5);
  const bf16* g_p = C(6);  const bf16* b_p = C(7);
  const bf16* Wqkv= C(8);  const bf16* bqkv= C(9);
  const bf16* Wo  = C(10); const bf16* bo  = C(11);
  const bf16* g_a = C(12); const bf16* b_a = C(13);
  const bf16* Wih_f = C(14); const bf16* Whh_f = C(15);
  const bf16* bih_f = C(16); const bf16* bhh_f = C(17);
  const bf16* Wih_b = C(18);
  const bf16* bih_b = C(20); const bf16* bhh_b = C(21);
  const bf16* Wtp = C(22); const bf16* btp = C(23);
  const bf16* Wn  = C(24); const bf16* bn_ = C(25);
  const bf16* We  = C(26); const bf16* be  = C(27);
  const bf16* Wa  = C(28); const bf16* ba  = C(29);
  const bf16* g_g = C(30); const bf16* b_g = C(31);
  const bf16* Remb= C(32);
  const bf16* Wg  = C(33); const bf16* bg  = C(34);
  const bf16* Wf  = C(35); const bf16* bff = C(36);
  const bf16* g_f = C(37); const bf16* b_f = C(38);
  const bf16* W1  = C(39); const bf16* b1  = C(40);
  const bf16* W2  = C(41); const bf16* b2  = C(42);
  const bf16* xc  = C(0);
  #undef C

  bf16*  outb = (bf16*)d_out;
  float* outf = (float*)d_out;
  bf16*  h1     = (bf16*)(ws + base);                 // 39,321,600 B
  bf16*  Wpp    = (bf16*)(ws + base + 196608000LL);   // 8192 B
  bf16*  An_pad = (bf16*)(ws + base + 196616192LL);   // 28672 B
  bf16*  ht_pad = (bf16*)(ws + base + 196644864LL);   // 458752 B
  bf16*  hb2g   = (bf16*)(ws + base + 197103616LL);   // 458752 B

  k_detect<<<1, 256, 0, stream>>>((const unsigned int*)d_in[0], flag);
  k_canon <<<dim3(64, nf), 256, 0, stream>>>(ca, flag, canon);
  k_prep  <<<1024, 256, 0, stream>>>(Wp, A_norm, Wpp, An_pad, ht_pad, hb2g);
  k_fat   <<<1600, 256, 0, stream>>>(xc, Wpp, bp, g_p, b_p, Wqkv, bqkv,
                                     Wo, bo, g_a, b_a, h1);
  k_lstm  <<<100,  512, 0, stream>>>(Whh_f, Wih_f, bih_f, bhh_f, h1,
                                     Wih_b, bih_b, bhh_b, Wtp, btp, ht_pad,
                                     flag, outb, outf);
  k_spat1 <<<16,   512, 0, stream>>>(ht_pad, Hinc, Wn, bn_, We, be, Wa, ba,
                                     g_g, b_g, hb2g);
  k_spat2 <<<16,   512, 0, stream>>>(hb2g, An_pad, Wg, bg, Remb, mem, ht_pad,
                                     Wf, bff, g_f, b_f, W1, b1, W2, b2,
                                     flag, outb, outf);
}

// Round 12
// 503.736 us; speedup vs baseline: 1.1281x; 1.1281x over previous
//
#include <hip/hip_runtime.h>
#include <hip/hip_bf16.h>

typedef __hip_bfloat16 bf16;
typedef __attribute__((ext_vector_type(8))) short bf8v;   // 8 bf16 (4 VGPRs)
typedef __attribute__((ext_vector_type(4))) short s4v;
typedef __attribute__((ext_vector_type(4))) float f4v;

#define DEV __device__ __forceinline__

DEV float b2f(bf16 v){ return __bfloat162float(v); }
DEV bf16 f2b(float v){ return __float2bfloat16(v); }
DEV short f2bs(float v){ bf16 t = __float2bfloat16(v); return *reinterpret_cast<short*>(&t); }
DEV float s2f(short s){ return __uint_as_float(((unsigned int)(unsigned short)s) << 16); }
DEV float rcpf_(float x){ return __builtin_amdgcn_rcpf(x); }
DEV float sigf(float x){ return rcpf_(1.0f + __expf(-x)); }
DEV float tanhfast(float x){
  x = fminf(fmaxf(x, -15.0f), 15.0f);
  float e = __expf(-2.0f*x);
  return (1.0f - e)*rcpf_(1.0f + e);
}

DEV f4v mfma16(bf8v a, bf8v b, f4v c){
  return __builtin_amdgcn_mfma_f32_16x16x32_bf16(a, b, c, 0, 0, 0);
}

// ---------------------------------------------------------------------------
// K0a: dtype detector (fp32 vs bf16 inputs). flag[0]=1 -> bf16, 0 -> fp32.
// ---------------------------------------------------------------------------
__global__ void k_detect(const unsigned int* __restrict__ xw, int* __restrict__ flag){
  __shared__ int found;
  if (threadIdx.x == 0) found = 0;
  __syncthreads();
  int local = 0;
  for (int i = threadIdx.x; i < 4096; i += 256){
    unsigned int u = xw[i];
    unsigned int e = (u >> 7) & 0xFF;
    if (e >= 0x90) local = 1;
  }
  if (local) atomicOr(&found, 1);
  __syncthreads();
  if (threadIdx.x == 0) flag[0] = found ? 0 : 1;
}

// ---------------------------------------------------------------------------
// K0b: canonicalize all float inputs into a bf16 region in ws.
// ---------------------------------------------------------------------------
struct CArgs {
  const void* src[44];
  int n[44];
  int off[44];
};

__global__ void k_canon(CArgs a, const int* __restrict__ flag, bf16* __restrict__ dst){
  int id = blockIdx.y;
  int n = a.n[id];
  const void* s = a.src[id];
  bf16* d = dst + a.off[id];
  int stride = gridDim.x * blockDim.x;
  int i0 = blockIdx.x * blockDim.x + threadIdx.x;
  if (flag[0]){
    const bf16* sb = (const bf16*)s;
    for (int i = i0; i < n; i += stride) d[i] = sb[i];
  } else {
    const float* sf = (const float*)s;
    for (int i = i0; i < n; i += stride) d[i] = f2b(sf[i]);
  }
}

// ---------------------------------------------------------------------------
// K0c: prep padded operands: Wp->Wpp (128x32), A_norm->Anp (112x128),
// zero ht_pad (16x112x128) and hb2_pad (16x112x128).
// ---------------------------------------------------------------------------
__global__ void k_prep(const bf16* __restrict__ Wp, const bf16* __restrict__ An,
                       bf16* __restrict__ Wpp, bf16* __restrict__ Anp,
                       bf16* __restrict__ htp, bf16* __restrict__ hb2p){
  int stride = gridDim.x * blockDim.x;
  bf16 zero = f2b(0.0f);
  for (int i = blockIdx.x*blockDim.x + threadIdx.x; i < 477184; i += stride){
    if (i < 4096){
      int row = i >> 5, col = i & 31;
      Wpp[i] = (col < 26) ? Wp[row*26 + col] : zero;
    } else if (i < 18432){
      int j = i - 4096;
      int row = j >> 7, col = j & 127;
      Anp[j] = (row < 100 && col < 100) ? An[row*100 + col] : zero;
    } else if (i < 247808){
      htp[i - 18432] = zero;
    } else {
      hb2p[i - 247808] = zero;
    }
  }
}

// ---------------------------------------------------------------------------
// K_INAT: fused input-proj+LN+relu -> attention. grid = 1600, block = 256.
// Attention part is byte-identical to the proven round-10 k_attn
// (P/V stride 104, LDS 57856 B -> 2 blocks/CU). inproj writes h0 to LDS
// (for QKV) and to global (for k_oproj residual). xt overlays v_sh;
// x-flat staging overlays scr.
// ---------------------------------------------------------------------------
__global__ __launch_bounds__(256) void k_inat(const bf16* __restrict__ x,
    const bf16* __restrict__ Wpp, const bf16* __restrict__ bp,
    const bf16* __restrict__ gp, const bf16* __restrict__ bbp,
    const bf16* __restrict__ Wqkv, const bf16* __restrict__ bqkv,
    bf16* __restrict__ h0, bf16* __restrict__ attno){
  int bn = blockIdx.x;
  int tid = threadIdx.x;
  int w = tid >> 6;
  int lane = tid & 63;
  int l15 = lane & 15, quad = lane >> 4;

  __shared__ __align__(16) short h0s[96*136];    // 26112 B (P panels later)
  __shared__ __align__(16) short v_sh[4][32*104];// 26624 B (xt overlays start)
  __shared__ __align__(16) short scr[4][16*40];  // 5120 B (x-flat overlays)

  // P0: stage x flat (96x26 = 312 uint4 = 4992 B) into scr
  {
    const uint4* src = (const uint4*)(x + bn*2496);
    uint4* dst = (uint4*)scr;
    for (int u = tid; u < 312; u += 256) dst[u] = src[u];
  }
  __syncthreads();
  // P1: build xt (96x40, cols 26..39 zero) at start of v_sh
  short* xt = (short*)v_sh;
  {
    const short* xflat = (const short*)scr;
    for (int i = tid; i < 3840; i += 256){
      int row = i/40, col = i - row*40;
      xt[i] = (col < 26) ? xflat[row*26 + col] : (short)0;
    }
  }
  __syncthreads();
  // P2: inproj + bias + LN + relu -> h0s (LDS) + h0 (global)
  for (int m = w; m < 6; m += 4){
    bf8v a = *reinterpret_cast<const bf8v*>(xt + (m*16 + l15)*40 + quad*8);
    f4v acc[8];
    for (int n = 0; n < 8; ++n){
      bf8v bb = *reinterpret_cast<const bf8v*>(Wpp + (n*16 + l15)*32 + quad*8);
      f4v z = {0.f,0.f,0.f,0.f};
      acc[n] = mfma16(a, bb, z);
    }
    float sm[4], sq[4];
    #pragma unroll
    for (int r = 0; r < 4; ++r){ sm[r] = 0.f; sq[r] = 0.f; }
    #pragma unroll
    for (int n = 0; n < 8; ++n){
      int col = n*16 + l15;
      float bv = b2f(bp[col]);
      #pragma unroll
      for (int r = 0; r < 4; ++r){
        float v = acc[n][r] + bv;
        acc[n][r] = v;
        sm[r] += v; sq[r] += v*v;
      }
    }
    #pragma unroll
    for (int mask = 1; mask < 16; mask <<= 1)
      #pragma unroll
      for (int r = 0; r < 4; ++r){
        sm[r] += __shfl_xor(sm[r], mask);
        sq[r] += __shfl_xor(sq[r], mask);
      }
    #pragma unroll
    for (int r = 0; r < 4; ++r){
      float mean = sm[r]*(1.0f/128.0f);
      float var = fmaxf(sq[r]*(1.0f/128.0f) - mean*mean, 0.0f);
      float rs = rsqrtf(var + 1e-5f);
      #pragma unroll
      for (int n = 0; n < 8; ++n){
        int col = n*16 + l15;
        float y = fmaxf((acc[n][r] - mean)*rs*b2f(gp[col]) + b2f(bbp[col]), 0.0f);
        int row = m*16 + quad*4 + r;
        h0s[row*136 + col] = f2bs(y);
        h0[(bn*96 + row)*128 + col] = f2b(y);
      }
    }
  }
  __syncthreads();   // xt (v_sh) and x-flat (scr) now dead

  short* vp = v_sh[w];
  short* sw = scr[w];
  const float scl = 0.17677669529663687f;

  bf8v aq[6], bk[6];
  // Phase 1a: Q panels -> registers
  for (int m = 0; m < 6; ++m){
    bf8v a[4];
    #pragma unroll
    for (int kt = 0; kt < 4; ++kt)
      a[kt] = *reinterpret_cast<const bf8v*>(h0s + (m*16 + l15)*136 + kt*32 + quad*8);
    #pragma unroll
    for (int n0 = 0; n0 < 32; n0 += 16){
      int rq = w*32 + n0 + l15;
      bf8v b[4];
      #pragma unroll
      for (int kt = 0; kt < 4; ++kt)
        b[kt] = *reinterpret_cast<const bf8v*>(Wqkv + rq*128 + kt*32 + quad*8);
      float bias = b2f(bqkv[rq]);
      f4v acc = {0.f,0.f,0.f,0.f};
      #pragma unroll
      for (int kt = 0; kt < 4; ++kt) acc = mfma16(a[kt], b[kt], acc);
      #pragma unroll
      for (int r = 0; r < 4; ++r)
        sw[(quad*4 + r)*40 + n0 + l15] = f2bs((acc[r] + bias)*scl);
    }
    asm volatile("s_waitcnt lgkmcnt(0)" ::: "memory");
    aq[m] = *reinterpret_cast<const bf8v*>(sw + l15*40 + quad*8);
  }
  // Phase 1b: K panels -> registers
  for (int m = 0; m < 6; ++m){
    bf8v a[4];
    #pragma unroll
    for (int kt = 0; kt < 4; ++kt)
      a[kt] = *reinterpret_cast<const bf8v*>(h0s + (m*16 + l15)*136 + kt*32 + quad*8);
    #pragma unroll
    for (int n0 = 0; n0 < 32; n0 += 16){
      int rq = 128 + w*32 + n0 + l15;
      bf8v b[4];
      #pragma unroll
      for (int kt = 0; kt < 4; ++kt)
        b[kt] = *reinterpret_cast<const bf8v*>(Wqkv + rq*128 + kt*32 + quad*8);
      float bias = b2f(bqkv[rq]);
      f4v acc = {0.f,0.f,0.f,0.f};
      #pragma unroll
      for (int kt = 0; kt < 4; ++kt) acc = mfma16(a[kt], b[kt], acc);
      #pragma unroll
      for (int r = 0; r < 4; ++r)
        sw[(quad*4 + r)*40 + n0 + l15] = f2bs(acc[r] + bias);
    }
    asm volatile("s_waitcnt lgkmcnt(0)" ::: "memory");
    bk[m] = *reinterpret_cast<const bf8v*>(sw + l15*40 + quad*8);
  }
  // Phase 1c: V^T -> LDS (dim x seq)
  for (int m = 0; m < 6; ++m){
    bf8v a[4];
    #pragma unroll
    for (int kt = 0; kt < 4; ++kt)
      a[kt] = *reinterpret_cast<const bf8v*>(h0s + (m*16 + l15)*136 + kt*32 + quad*8);
    #pragma unroll
    for (int n0 = 0; n0 < 32; n0 += 16){
      int rq = 256 + w*32 + n0 + l15;
      bf8v b[4];
      #pragma unroll
      for (int kt = 0; kt < 4; ++kt)
        b[kt] = *reinterpret_cast<const bf8v*>(Wqkv + rq*128 + kt*32 + quad*8);
      float bias = b2f(bqkv[rq]);
      f4v acc = {0.f,0.f,0.f,0.f};
      #pragma unroll
      for (int kt = 0; kt < 4; ++kt) acc = mfma16(a[kt], b[kt], acc);
      s4v vs;
      #pragma unroll
      for (int r = 0; r < 4; ++r) vs[r] = f2bs(acc[r] + bias);
      *reinterpret_cast<s4v*>(vp + (n0 + l15)*104 + m*16 + quad*4) = vs;
    }
  }
  __syncthreads();   // h0s -> P panels

  short* pp = h0s + w*1664;   // 16 x 104 bf16 P panel per wave

  for (int m = 0; m < 6; ++m){
    f4v s[6];
    #pragma unroll
    for (int n = 0; n < 6; ++n){
      f4v z = {0.f,0.f,0.f,0.f};
      s[n] = mfma16(aq[m], bk[n], z);
    }
    float mr[4], sr[4];
    #pragma unroll
    for (int r = 0; r < 4; ++r){
      float m0 = fmaxf(fmaxf(s[0][r], s[1][r]), fmaxf(s[2][r], s[3][r]));
      mr[r] = fmaxf(m0, fmaxf(s[4][r], s[5][r]));
    }
    #pragma unroll
    for (int mask = 1; mask < 16; mask <<= 1)
      #pragma unroll
      for (int r = 0; r < 4; ++r) mr[r] = fmaxf(mr[r], __shfl_xor(mr[r], mask));
    #pragma unroll
    for (int r = 0; r < 4; ++r) sr[r] = 0.0f;
    #pragma unroll
    for (int n = 0; n < 6; ++n)
      #pragma unroll
      for (int r = 0; r < 4; ++r){
        float p = __expf(s[n][r] - mr[r]);
        s[n][r] = p;
        sr[r] += p;
      }
    #pragma unroll
    for (int mask = 1; mask < 16; mask <<= 1)
      #pragma unroll
      for (int r = 0; r < 4; ++r) sr[r] += __shfl_xor(sr[r], mask);
    #pragma unroll
    for (int n = 0; n < 6; ++n)
      #pragma unroll
      for (int r = 0; r < 4; ++r)
        pp[(quad*4 + r)*104 + n*16 + l15] = f2bs(s[n][r]);
    asm volatile("s_waitcnt lgkmcnt(0)" ::: "memory");
    f4v o0 = {0.f,0.f,0.f,0.f}, o1 = {0.f,0.f,0.f,0.f};
    #pragma unroll
    for (int ksi = 0; ksi < 3; ++ksi){
      bf8v ap  = *reinterpret_cast<const bf8v*>(pp + l15*104 + ksi*32 + quad*8);
      bf8v bv0 = *reinterpret_cast<const bf8v*>(vp + l15*104 + ksi*32 + quad*8);
      bf8v bv1 = *reinterpret_cast<const bf8v*>(vp + (16 + l15)*104 + ksi*32 + quad*8);
      o0 = mfma16(ap, bv0, o0);
      o1 = mfma16(ap, bv1, o1);
    }
    #pragma unroll
    for (int r = 0; r < 4; ++r){
      float inv = 1.0f/sr[r];
      int row = bn*96 + m*16 + quad*4 + r;
      attno[row*128 + w*32 + l15]      = f2b(o0[r]*inv);
      attno[row*128 + w*32 + 16 + l15] = f2b(o1[r]*inv);
    }
  }
}

// ---------------------------------------------------------------------------
// K3: out-proj + residual + LN, MFMA. grid = 1200, block = 256.
// ---------------------------------------------------------------------------
__global__ __launch_bounds__(256) void k_oproj(const bf16* __restrict__ attno,
    const bf16* __restrict__ h0, const bf16* __restrict__ Wo,
    const bf16* __restrict__ bo, const bf16* __restrict__ ga,
    const bf16* __restrict__ ba_, bf16* __restrict__ h1){
  int rt = blockIdx.x;
  int tid = threadIdx.x;
  int w = tid >> 6, lane = tid & 63;
  int l15 = lane & 15, quad = lane >> 4;
  __shared__ __align__(16) short atile[128*136];
  {
    const uint4* src = (const uint4*)(attno + rt*16384);
    uint4* dst = (uint4*)atile;
    for (int u = tid; u < 2048; u += 256){
      int r = u >> 4, c = u & 15;
      dst[r*17 + c] = src[u];
    }
  }
  __syncthreads();
  int m0 = w*32;
  bf8v a[2][4];
  #pragma unroll
  for (int m = 0; m < 2; ++m)
    #pragma unroll
    for (int ksi = 0; ksi < 4; ++ksi)
      a[m][ksi] = *reinterpret_cast<const bf8v*>(atile + (m0 + m*16 + l15)*136 + ksi*32 + quad*8);
  f4v acc[2][8];
  #pragma unroll
  for (int m = 0; m < 2; ++m)
    #pragma unroll
    for (int n = 0; n < 8; ++n) acc[m][n] = (f4v){0.f,0.f,0.f,0.f};
  for (int n = 0; n < 8; ++n){
    int G = n*16 + l15;
    bf8v b[4];
    #pragma unroll
    for (int ksi = 0; ksi < 4; ++ksi)
      b[ksi] = *reinterpret_cast<const bf8v*>(Wo + G*128 + ksi*32 + quad*8);
    #pragma unroll
    for (int m = 0; m < 2; ++m)
      #pragma unroll
      for (int ksi = 0; ksi < 4; ++ksi)
        acc[m][n] = mfma16(a[m][ksi], b[ksi], acc[m][n]);
  }
  #pragma unroll
  for (int m = 0; m < 2; ++m){
    int rowbase = rt*128 + m0 + m*16;
    #pragma unroll
    for (int n = 0; n < 8; ++n){
      int col = n*16 + l15;
      float bia = b2f(bo[col]);
      #pragma unroll
      for (int r = 0; r < 4; ++r)
        acc[m][n][r] += bia + b2f(h0[(rowbase + quad*4 + r)*128 + col]);
    }
    float sm[4], sq[4];
    #pragma unroll
    for (int r = 0; r < 4; ++r){ sm[r] = 0.f; sq[r] = 0.f; }
    #pragma unroll
    for (int n = 0; n < 8; ++n)
      #pragma unroll
      for (int r = 0; r < 4; ++r){
        float v = acc[m][n][r];
        sm[r] += v; sq[r] += v*v;
      }
    #pragma unroll
    for (int mask = 1; mask < 16; mask <<= 1)
      #pragma unroll
      for (int r = 0; r < 4; ++r){
        sm[r] += __shfl_xor(sm[r], mask);
        sq[r] += __shfl_xor(sq[r], mask);
      }
    float mean[4], rs[4];
    #pragma unroll
    for (int r = 0; r < 4; ++r){
      mean[r] = sm[r]*(1.0f/128.0f);
      float var = fmaxf(sq[r]*(1.0f/128.0f) - mean[r]*mean[r], 0.0f);
      rs[r] = rsqrtf(var + 1e-5f);
    }
    #pragma unroll
    for (int n = 0; n < 8; ++n){
      int col = n*16 + l15;
      float gv = b2f(ga[col]), bv = b2f(ba_[col]);
      #pragma unroll
      for (int r = 0; r < 4; ++r){
        float y = (acc[m][n][r] - mean[r])*rs[r]*gv + bv;
        h1[(rowbase + quad*4 + r)*128 + col] = f2b(y);
      }
    }
  }
}

// ---------------------------------------------------------------------------
// K5: fused forward LSTM + backward single-step + temporal projection.
// grid = 100 (16 samples/block), block = 512 (8 waves).
// ---------------------------------------------------------------------------
__global__ __launch_bounds__(512,1) void k_lstm(const bf16* __restrict__ Whh,
    const bf16* __restrict__ Wih, const bf16* __restrict__ bih,
    const bf16* __restrict__ bhh, const bf16* __restrict__ h1,
    const bf16* __restrict__ Wihb, const bf16* __restrict__ bihb,
    const bf16* __restrict__ bhhb, const bf16* __restrict__ Wtp,
    const bf16* __restrict__ btp, bf16* __restrict__ ht_pad,
    const int* __restrict__ flag, bf16* __restrict__ outb,
    float* __restrict__ outf){
  int bn0 = blockIdx.x * 16;
  int tid = threadIdx.x;
  int w = tid >> 6, lane = tid & 63;
  int l15 = lane & 15, quad = lane >> 4;
  __shared__ __align__(16) short hbuf[2][16*136];
  __shared__ __align__(16) short xbuf[2][16*136];
  __shared__ __align__(16) short ycat[16*264];

  bf8v whh[4][4], wih[4][4];
  float bias[4];
  #pragma unroll
  for (int role = 0; role < 4; ++role){
    int G = role*128 + w*16 + l15;
    #pragma unroll
    for (int kt = 0; kt < 4; ++kt){
      whh[role][kt] = *reinterpret_cast<const bf8v*>(Whh + G*128 + kt*32 + quad*8);
      wih[role][kt] = *reinterpret_cast<const bf8v*>(Wih + G*128 + kt*32 + quad*8);
    }
    bias[role] = b2f(bih[G]) + b2f(bhh[G]);
  }
  const uint4* h1u4 = (const uint4*)h1;
  int srow = tid >> 4, scol = tid & 15;

  for (int i = tid; i < 16*136; i += 512) hbuf[0][i] = 0;
  if (tid < 256)
    ((uint4*)xbuf[0])[srow*17 + scol] = h1u4[((bn0 + srow)*96 + 0)*16 + scol];
  f4v c0 = {0.f,0.f,0.f,0.f};
  uint4 xpre;
  if (tid < 256) xpre = h1u4[((bn0 + srow)*96 + 1)*16 + scol];
  __syncthreads();

  f4v accx[4];
  {
    bf8v ax[4];
    #pragma unroll
    for (int kt = 0; kt < 4; ++kt)
      ax[kt] = *reinterpret_cast<const bf8v*>(xbuf[0] + l15*136 + kt*32 + quad*8);
    #pragma unroll
    for (int role = 0; role < 4; ++role){
      f4v z = {0.f,0.f,0.f,0.f};
      #pragma unroll
      for (int kt = 0; kt < 4; ++kt) z = mfma16(ax[kt], wih[role][kt], z);
      accx[role] = z;
    }
  }
  if (tid < 256) ((uint4*)xbuf[1])[srow*17 + scol] = xpre;
  if (tid < 256) xpre = h1u4[((bn0 + srow)*96 + 2)*16 + scol];
  __syncthreads();

  for (int t = 0; t < 96; ++t){
    int cur = t & 1, nxt = cur ^ 1;
    bf8v ah[4], axn[4];
    #pragma unroll
    for (int kt = 0; kt < 4; ++kt){
      ah[kt]  = *reinterpret_cast<const bf8v*>(hbuf[cur] + l15*136 + kt*32 + quad*8);
      axn[kt] = *reinterpret_cast<const bf8v*>(xbuf[nxt] + l15*136 + kt*32 + quad*8);
    }
    f4v acc[4];
    #pragma unroll
    for (int role = 0; role < 4; ++role){
      f4v z = accx[role];
      #pragma unroll
      for (int kt = 0; kt < 4; ++kt) z = mfma16(ah[kt], whh[role][kt], z);
      acc[role] = z;
    }
    #pragma unroll
    for (int role = 0; role < 4; ++role){
      f4v z = {0.f,0.f,0.f,0.f};
      #pragma unroll
      for (int kt = 0; kt < 4; ++kt) z = mfma16(axn[kt], wih[role][kt], z);
      accx[role] = z;
    }
    float hreg[4];
    #pragma unroll
    for (int r = 0; r < 4; ++r){
      float i_ = acc[0][r] + bias[0];
      float f_ = acc[1][r] + bias[1];
      float g_ = acc[2][r] + bias[2];
      float o_ = acc[3][r] + bias[3];
      float c  = sigf(f_)*c0[r] + sigf(i_)*tanhfast(g_);
      hreg[r]  = sigf(o_)*tanhfast(c);
      c0[r] = c;
    }
    #pragma unroll
    for (int r = 0; r < 4; ++r)
      hbuf[nxt][(quad*4 + r)*136 + w*16 + l15] = f2bs(hreg[r]);
    if (tid < 256){
      ((uint4*)xbuf[cur])[srow*17 + scol] = xpre;
      int tl = (t + 3 < 96) ? t + 3 : 95;
      xpre = h1u4[((bn0 + srow)*96 + tl)*16 + scol];
    }
    __syncthreads();
  }
  // ---- epilogue: bwd single-step (zero state) + Wtp projection ----
  for (int idx = tid; idx < 2048; idx += 512){
    int r = idx >> 7, d = idx & 127;
    ycat[r*264 + d] = hbuf[0][r*136 + d];
  }
  {
    bf8v ax[4];
    #pragma unroll
    for (int kt = 0; kt < 4; ++kt)
      ax[kt] = *reinterpret_cast<const bf8v*>(xbuf[0] + l15*136 + kt*32 + quad*8);
    int col = w*16 + l15;
    f4v gi = {0.f,0.f,0.f,0.f}, gg = {0.f,0.f,0.f,0.f}, go = {0.f,0.f,0.f,0.f};
    #pragma unroll
    for (int kt = 0; kt < 4; ++kt){
      gi = mfma16(ax[kt], *reinterpret_cast<const bf8v*>(Wihb + col*128 + kt*32 + quad*8), gi);
      gg = mfma16(ax[kt], *reinterpret_cast<const bf8v*>(Wihb + (256 + col)*128 + kt*32 + quad*8), gg);
      go = mfma16(ax[kt], *reinterpret_cast<const bf8v*>(Wihb + (384 + col)*128 + kt*32 + quad*8), go);
    }
    float bi = b2f(bihb[col])       + b2f(bhhb[col]);
    float bg = b2f(bihb[256 + col]) + b2f(bhhb[256 + col]);
    float bo = b2f(bihb[384 + col]) + b2f(bhhb[384 + col]);
    #pragma unroll
    for (int r = 0; r < 4; ++r){
      float c  = sigf(gi[r] + bi) * tanhfast(gg[r] + bg);
      float yb = sigf(go[r] + bo) * tanhfast(c);
      ycat[(quad*4 + r)*264 + 128 + col] = f2bs(yb);
    }
  }
  __syncthreads();
  {
    int col = w*16 + l15;
    f4v z = {0.f,0.f,0.f,0.f};
    #pragma unroll
    for (int kt = 0; kt < 8; ++kt){
      bf8v a = *reinterpret_cast<const bf8v*>(ycat + l15*264 + kt*32 + quad*8);
      bf8v bb = *reinterpret_cast<const bf8v*>(Wtp + col*256 + kt*32 + quad*8);
      z = mfma16(a, bb, z);
    }
    float bt = b2f(btp[col]);
    #pragma unroll
    for (int r = 0; r < 4; ++r){
      int rowg = bn0 + quad*4 + r;
      float v = z[r] + bt;
      int bb_ = rowg/100, nn = rowg - bb_*100;
      ht_pad[(bb_*112 + nn)*128 + col] = f2b(v);
      int oi = 206400 + rowg*128 + col;
      if (flag[0]) outb[oi] = f2b(v); else outf[oi] = v;
    }
  }
}

// ---------------------------------------------------------------------------
// K6: spatial part A (hyperedge attention + node LN). grid = 16, block = 512.
// ---------------------------------------------------------------------------
__global__ __launch_bounds__(512,1) void k_spat1(
    const bf16* __restrict__ ht_pad, const bf16* __restrict__ Hinc,
    const bf16* __restrict__ Wn, const bf16* __restrict__ bn_,
    const bf16* __restrict__ We, const bf16* __restrict__ be,
    const bf16* __restrict__ Wa, const bf16* __restrict__ ba,
    const bf16* __restrict__ gg_, const bf16* __restrict__ bg_,
    bf16* __restrict__ hb2g){
  int b = blockIdx.x, tid = threadIdx.x;
  int w = tid >> 6, lane = tid & 63, l15 = lane & 15, quad = lane >> 4;
  __shared__ __align__(16) short htb[112*136];
  __shared__ __align__(16) short mtile[16*136];
  __shared__ float HincS[1600];
  __shared__ float wts[1600];
  __shared__ float eeS[16*128];
  __shared__ float scE[16], degS[16], part[128];

  {
    const uint4* src = (const uint4*)(ht_pad + b*14336);
    uint4* dst = (uint4*)htb;
    for (int u = tid; u < 1792; u += 512){
      int r = u >> 4, c = u & 15;
      dst[r*17 + c] = src[u];
    }
  }
  for (int i = tid; i < 1600; i += 512) HincS[i] = b2f(Hinc[i]);
  __syncthreads();
  if (tid < 16){
    float s = 0.0f;
    for (int n = 0; n < 100; ++n) s += HincS[n*16 + tid];
    degS[tid] = s;
  }
  __syncthreads();
  for (int it = 0; it < 4; ++it){
    int idx = tid + it*512;
    int e = idx >> 7, d = idx & 127;
    float s = 0.0f;
    for (int n = 0; n < 100; ++n)
      s += HincS[n*16 + e] * s2f(htb[n*136 + d]);
    mtile[e*136 + d] = f2bs(s * rcpf_(degS[e] + 1e-8f));
  }
  __syncthreads();
  {
    bf8v a[4];
    #pragma unroll
    for (int kt = 0; kt < 4; ++kt)
      a[kt] = *reinterpret_cast<const bf8v*>(mtile + l15*136 + kt*32 + quad*8);
    int col = w*16 + l15;
    f4v z = {0.f,0.f,0.f,0.f};
    #pragma unroll
    for (int kt = 0; kt < 4; ++kt)
      z = mfma16(a[kt], *reinterpret_cast<const bf8v*>(Wn + col*128 + kt*32 + quad*8), z);
    float bnv = b2f(bn_[col]);
    __syncthreads();
    #pragma unroll
    for (int r = 0; r < 4; ++r){
      int e = quad*4 + r;
      float ratio = degS[e] * rcpf_(degS[e] + 1e-8f);
      mtile[e*136 + col] = f2bs(z[r] + bnv*ratio);
    }
  }
  __syncthreads();
  {
    bf8v a[4];
    #pragma unroll
    for (int kt = 0; kt < 4; ++kt)
      a[kt] = *reinterpret_cast<const bf8v*>(mtile + l15*136 + kt*32 + quad*8);
    int col = w*16 + l15;
    f4v z = {0.f,0.f,0.f,0.f};
    #pragma unroll
    for (int kt = 0; kt < 4; ++kt)
      z = mfma16(a[kt], *reinterpret_cast<const bf8v*>(We + col*128 + kt*32 + quad*8), z);
    float bev = b2f(be[col]);
    #pragma unroll
    for (int r = 0; r < 4; ++r)
      eeS[(quad*4 + r)*128 + col] = z[r] + bev;
  }
  __syncthreads();
  if (tid < 128){
    int e = tid >> 3, j = tid & 7;
    float s = 0.0f;
    for (int d = j*16; d < j*16 + 16; ++d)
      s += eeS[e*128 + d] * b2f(Wa[d]);
    part[tid] = s;
  }
  __syncthreads();
  if (tid < 16){
    float s = b2f(ba[0]);
    for (int j = 0; j < 8; ++j) s += part[tid*8 + j];
    scE[tid] = s;
  }
  __syncthreads();
  if (tid < 100){
    float sc[16], mx = -1e30f;
    for (int e = 0; e < 16; ++e){
      sc[e] = (HincS[tid*16 + e] > 0.0f) ? scE[e] : -1e30f;
      mx = fmaxf(mx, sc[e]);
    }
    float sum = 0.0f, tmp[16];
    for (int e = 0; e < 16; ++e){
      tmp[e] = (sc[e] > -1e29f) ? __expf(sc[e] - mx) : 0.0f;
      sum += tmp[e];
    }
    float inv = (sum > 0.0f) ? rcpf_(sum) : 0.0f;
    for (int e = 0; e < 16; ++e) wts[tid*16 + e] = tmp[e]*inv;
  }
  __syncthreads();
  for (int it = 0; it < 13; ++it){
    int n = it*8 + w;
    if (n < 100){
      int d0 = lane*2;
      float s0 = s2f(htb[n*136 + d0]);
      float s1 = s2f(htb[n*136 + d0 + 1]);
      for (int e = 0; e < 16; ++e){
        float wv = wts[n*16 + e];
        s0 += wv * eeS[e*128 + d0];
        s1 += wv * eeS[e*128 + d0 + 1];
      }
      float sum = s0 + s1, sq = s0*s0 + s1*s1;
      #pragma unroll
      for (int mask = 1; mask < 64; mask <<= 1){
        sum += __shfl_xor(sum, mask);
        sq  += __shfl_xor(sq, mask);
      }
      float mean = sum*(1.0f/128.0f);
      float var = fmaxf(sq*(1.0f/128.0f) - mean*mean, 0.0f);
      float rs = rsqrtf(var + 1e-5f);
      float y0 = (s0 - mean)*rs*b2f(gg_[d0])     + b2f(bg_[d0]);
      float y1 = (s1 - mean)*rs*b2f(gg_[d0 + 1]) + b2f(bg_[d0 + 1]);
      hb2g[b*14336 + n*128 + d0]     = f2b(y0);
      hb2g[b*14336 + n*128 + d0 + 1] = f2b(y1);
    }
  }
}

// ---------------------------------------------------------------------------
// K7: spatial part B (GCN + fusion + head). grid = 16, block = 512.
// ---------------------------------------------------------------------------
__global__ __launch_bounds__(512,1) void k_spat2(
    const bf16* __restrict__ hb2g, const bf16* __restrict__ Anp,
    const bf16* __restrict__ Wg, const bf16* __restrict__ bgc,
    const bf16* __restrict__ Remb, const int* __restrict__ mem,
    const bf16* __restrict__ ht_pad,
    const bf16* __restrict__ Wf, const bf16* __restrict__ bf_,
    const bf16* __restrict__ gf, const bf16* __restrict__ b_f,
    const bf16* __restrict__ W1, const bf16* __restrict__ b1,
    const bf16* __restrict__ W2, const bf16* __restrict__ b2,
    const int* __restrict__ flag, bf16* __restrict__ outb,
    float* __restrict__ outf){
  int b = blockIdx.x, tid = threadIdx.x;
  int w = tid >> 6, lane = tid & 63, l15 = lane & 15, quad = lane >> 4;
  __shared__ __align__(16) short regA[128*136];
  __shared__ __align__(16) short regB[112*136];

  for (int i = tid; i < 128*136; i += 512) regA[i] = 0;
  __syncthreads();
  {
    int c0 = w*16;
    bf8v bw[4];
    #pragma unroll
    for (int kt = 0; kt < 4; ++kt)
      bw[kt] = *reinterpret_cast<const bf8v*>(Wg + (c0 + l15)*128 + kt*32 + quad*8);
    for (int m = 0; m < 7; ++m){
      f4v z = {0.f,0.f,0.f,0.f};
      #pragma unroll
      for (int kt = 0; kt < 4; ++kt){
        bf8v a = *reinterpret_cast<const bf8v*>(hb2g + b*14336 + (m*16 + l15)*128 + kt*32 + quad*8);
        z = mfma16(a, bw[kt], z);
      }
      s4v vs;
      #pragma unroll
      for (int r = 0; r < 4; ++r) vs[r] = f2bs(z[r]);
      *reinterpret_cast<s4v*>(regA + (c0 + l15)*136 + m*16 + quad*4) = vs;
    }
  }
  __syncthreads();
  {
    int c0 = w*16;
    for (int m = 0; m < 7; ++m){
      f4v z = {0.f,0.f,0.f,0.f};
      #pragma unroll
      for (int kt = 0; kt < 4; ++kt){
        bf8v a  = *reinterpret_cast<const bf8v*>(Anp + (m*16 + l15)*128 + kt*32 + quad*8);
        bf8v bb = *reinterpret_cast<const bf8v*>(regA + (c0 + l15)*136 + kt*32 + quad*8);
        z = mfma16(a, bb, z);
      }
      #pragma unroll
      for (int r = 0; r < 4; ++r){
        int row = m*16 + quad*4 + r, col = c0 + l15;
        if (row < 100){
          float v = fmaxf(z[r] + b2f(bgc[col]), 0.0f);
          float o = b2f(hb2g[b*14336 + row*128 + col]) + v
                  + b2f(Remb[mem[row]*128 + col]);
          int oi = 1600 + (b*100 + row)*128 + col;
          if (flag[0]) outb[oi] = f2b(o); else outf[oi] = o;
          regB[row*136 + col] = f2bs(o);
        } else {
          regB[row*136 + col] = 0;
        }
      }
    }
  }
  __syncthreads();
  if (w < 7){
    int m = w;
    f4v acc[8];
    for (int n = 0; n < 8; ++n){
      f4v z = {0.f,0.f,0.f,0.f};
      #pragma unroll
      for (int kt = 0; kt < 4; ++kt){
        bf8v a  = *reinterpret_cast<const bf8v*>(ht_pad + b*14336 + (m*16 + l15)*128 + kt*32 + quad*8);
        bf8v bb = *reinterpret_cast<const bf8v*>(Wf + (n*16 + l15)*256 + kt*32 + quad*8);
        z = mfma16(a, bb, z);
      }
      #pragma unroll
      for (int kt = 0; kt < 4; ++kt){
        bf8v a  = *reinterpret_cast<const bf8v*>(regB + (m*16 + l15)*136 + kt*32 + quad*8);
        bf8v bb = *reinterpret_cast<const bf8v*>(Wf + (n*16 + l15)*256 + 128 + kt*32 + quad*8);
        z = mfma16(a, bb, z);
      }
      acc[n] = z;
    }
    float sm[4], sq[4];
    #pragma unroll
    for (int r = 0; r < 4; ++r){ sm[r] = 0.f; sq[r] = 0.f; }
    #pragma unroll
    for (int n = 0; n < 8; ++n){
      int col = n*16 + l15;
      float bv = b2f(bf_[col]);
      #pragma unroll
      for (int r = 0; r < 4; ++r){
        float v = acc[n][r] + bv;
        acc[n][r] = v;
        sm[r] += v; sq[r] += v*v;
      }
    }
    #pragma unroll
    for (int mask = 1; mask < 16; mask <<= 1)
      #pragma unroll
      for (int r = 0; r < 4; ++r){
        sm[r] += __shfl_xor(sm[r], mask);
        sq[r] += __shfl_xor(sq[r], mask);
      }
    #pragma unroll
    for (int r = 0; r < 4; ++r){
      float mean = sm[r]*(1.0f/128.0f);
      float var = fmaxf(sq[r]*(1.0f/128.0f) - mean*mean, 0.0f);
      float rs = rsqrtf(var + 1e-5f);
      #pragma unroll
      for (int n = 0; n < 8; ++n){
        int col = n*16 + l15;
        float y = fmaxf((acc[n][r] - mean)*rs*b2f(gf[col]) + b2f(b_f[col]), 0.0f);
        regA[(m*16 + quad*4 + r)*136 + col] = f2bs(y);
      }
    }
  }
  __syncthreads();
  if (w < 7){
    int m = w;
    for (int n = 0; n < 4; ++n){
      f4v z = {0.f,0.f,0.f,0.f};
      #pragma unroll
      for (int kt = 0; kt < 4; ++kt){
        bf8v a  = *reinterpret_cast<const bf8v*>(regA + (m*16 + l15)*136 + kt*32 + quad*8);
        bf8v bb = *reinterpret_cast<const bf8v*>(W1 + (n*16 + l15)*128 + kt*32 + quad*8);
        z = mfma16(a, bb, z);
      }
      #pragma unroll
      for (int r = 0; r < 4; ++r){
        int row = m*16 + quad*4 + r, col = n*16 + l15;
        regB[row*72 + col] = f2bs(fmaxf(z[r] + b2f(b1[col]), 0.0f));
      }
    }
  }
  __syncthreads();
  if (tid < 100){
    float s = b2f(b2[0]);
    for (int d = 0; d < 64; ++d)
      s += s2f(regB[tid*72 + d]) * b2f(W2[d]);
    int oi = b*100 + tid;
    if (flag[0]) outb[oi] = f2b(s); else outf[oi] = s;
  }
}

// ---------------------------------------------------------------------------

extern "C" void kernel_launch(void* const* d_in, const int* in_sizes, int n_in,
                              void* d_out, int out_size, void* d_ws, size_t ws_size,
                              hipStream_t stream){
  (void)n_in; (void)out_size; (void)ws_size;
  const int* mem = (const int*)d_in[3];

  CArgs ca;
  int coff[43];
  int nf = 0;
  long long off = 0;
  for (int i = 0; i < 43; ++i){
    if (i == 3){ coff[i] = -1; continue; }
    coff[i] = (int)off;
    ca.src[nf] = d_in[i];
    ca.n[nf]   = in_sizes[i];
    ca.off[nf] = (int)off;
    ++nf;
    off += (long long)((in_sizes[i] + 7) & ~7);
  }
  char* ws = (char*)d_ws;
  bf16* canon = (bf16*)ws;
  long long canonBytes = ((off*2 + 255)/256)*256;
  int* flag = (int*)(ws + canonBytes);
  long long base = canonBytes + 256;

  #define C(i) (canon + coff[i])
  const bf16* A_norm = C(1);
  const bf16* Hinc   = C(2);
  const bf16* Wp  = C(4);  const bf16* bp  = C(5);
  const bf16* g_p = C(6);  const bf16* b_p = C(7);
  const bf16* Wqkv= C(8);  const bf16* bqkv= C(9);
  const bf16* Wo  = C(10); const bf16* bo  = C(11);
  const bf16* g_a = C(12); const bf16* b_a = C(13);
  const bf16* Wih_f = C(14); const bf16* Whh_f = C(15);
  const bf16* bih_f = C(16); const bf16* bhh_f = C(17);
  const bf16* Wih_b = C(18);
  const bf16* bih_b = C(20); const bf16* bhh_b = C(21);
  const bf16* Wtp = C(22); const bf16* btp = C(23);
  const bf16* Wn  = C(24); const bf16* bn_ = C(25);
  const bf16* We  = C(26); const bf16* be  = C(27);
  const bf16* Wa  = C(28); const bf16* ba  = C(29);
  const bf16* g_g = C(30); const bf16* b_g = C(31);
  const bf16* Remb= C(32);
  const bf16* Wg  = C(33); const bf16* bg  = C(34);
  const bf16* Wf  = C(35); const bf16* bff = C(36);
  const bf16* g_f = C(37); const bf16* b_f = C(38);
  const bf16* W1  = C(39); const bf16* b1  = C(40);
  const bf16* W2  = C(41); const bf16* b2  = C(42);
  const bf16* xc  = C(0);
  #undef C

  bf16*  outb = (bf16*)d_out;
  float* outf = (float*)d_out;
  bf16*  h1     = (bf16*)(ws + base);                 // 39,321,600 B
  bf16*  h0     = (bf16*)(ws + base + 39321600LL);    // 39,321,600 B
  bf16*  attno  = (bf16*)(ws + base + 78643200LL);    // 39,321,600 B
  bf16*  Wpp    = (bf16*)(ws + base + 196608000LL);   // 8192 B
  bf16*  An_pad = (bf16*)(ws + base + 196616192LL);   // 28672 B
  bf16*  ht_pad = (bf16*)(ws + base + 196644864LL);   // 458752 B
  bf16*  hb2g   = (bf16*)(ws + base + 197103616LL);   // 458752 B

  k_detect<<<1, 256, 0, stream>>>((const unsigned int*)d_in[0], flag);
  k_canon <<<dim3(64, nf), 256, 0, stream>>>(ca, flag, canon);
  k_prep  <<<1024, 256, 0, stream>>>(Wp, A_norm, Wpp, An_pad, ht_pad, hb2g);
  k_inat  <<<1600, 256, 0, stream>>>(xc, Wpp, bp, g_p, b_p, Wqkv, bqkv,
                                     h0, attno);
  k_oproj <<<1200, 256, 0, stream>>>(attno, h0, Wo, bo, g_a, b_a, h1);
  k_lstm  <<<100,  512, 0, stream>>>(Whh_f, Wih_f, bih_f, bhh_f, h1,
                                     Wih_b, bih_b, bhh_b, Wtp, btp, ht_pad,
                                     flag, outb, outf);
  k_spat1 <<<16,   512, 0, stream>>>(ht_pad, Hinc, Wn, bn_, We, be, Wa, ba,
                                     g_g, b_g, hb2g);
  k_spat2 <<<16,   512, 0, stream>>>(hb2g, An_pad, Wg, bg, Remb, mem, ht_pad,
                                     Wf, bff, g_f, b_f, W1, b1, W2, b2,
                                     flag, outb, outf);
}